// Round 8
// baseline (1042.340 us; speedup 1.0000x reference)
//
#include <hip/hip_runtime.h>
#include <math.h>

#define Bn   8
#define Cn   256
#define HWn  4096
#define FB   (Cn * HWn)      // 1048576 elems per batch-field
#define NTOT (Bn * FB)       // 8388608 elems per field
#define TEND 1.0
#define EPSK 1e-12f
#define NT   64              // apply N-tile (positions) — full 256B lines
#define RS   40              // staging row stride (shorts); 16 data slots + pad
#define WTS  68              // wt / tred row stride (floats)

typedef float f32x4 __attribute__((ext_vector_type(4)));
typedef short bf16x8 __attribute__((ext_vector_type(8)));

__device__ inline float b2f(unsigned int u) {
    return __uint_as_float(u << 16);
}
__device__ inline unsigned short f2b(float f) {  // RNE
    unsigned u = __float_as_uint(f);
    unsigned r = u + 0x7FFFu + ((u >> 16) & 1u);
    return (unsigned short)(r >> 16);
}

// acc layout (floats, 8 batches each):
//   D[k][j] at acc[(k*8+j)*8 + b];  Nsq[j] at acc[512 + j*8 + b];  coords at acc+576

__global__ void init_kernel(float* __restrict__ p) {
    for (int i = threadIdx.x; i < 1024; i += 256) p[i] = 0.0f;
}

// ---- split W into bf16 hi/lo in MFMA-A staged layout ----
// layout: Whs[((kc*16+mt)*64+lane)*8+j] = bf16 of W[mt*16+(lane&15)][kc*32+(lane>>4)*8+j]
__global__ void wsplit_kernel(const float* __restrict__ W,
                              unsigned short* __restrict__ Whs,
                              unsigned short* __restrict__ Wls) {
    int kc = blockIdx.x, mt = blockIdx.y, l = threadIdx.x;
    int m = mt * 16 + (l & 15);
    int k0 = kc * 32 + (l >> 4) * 8;
#pragma unroll
    for (int j = 0; j < 8; ++j) {
        float wv = W[m * 256 + k0 + j];
        unsigned short h = f2b(wv);
        unsigned short lo = f2b(wv - b2f(h));
        int idx = ((kc * 16 + mt) * 64 + l) * 8 + j;
        Whs[idx] = h; Wls[idx] = lo;
    }
}

// ================= fused Krylov step K (K = 0..7), 512-thread blocks ===========
// One block per (tile, batch): 8 waves x 32 rows, 2 blocks/CU.
// ASYNC-STAGE SPLIT (this round's change): per k-chunk, global loads for chunk
// kc+1 are ISSUED into registers before the MFMAs of chunk kc, and CONSUMED
// (vmcnt wait + CGS + LDS write) after them — HBM latency hides under MFMA.
// Round 7 stalled ~900cy in stage() before each MFMA phase (92us regardless of
// traffic). W-fragment loads are issued before the prefetch so their in-order
// vmcnt wait does not drain the prefetch loads.
//   x = w - sum cj*basis (CGS) -> Q_{K-1} bf16; P = s0*xr, S = s0 staged hi/lo
//   (XOR-swizzled LDS, shfl-paired b32 writes); MFMA: ac += W@P, az += W@S.
// Epilogue: w' = ac - az*t (Z = W@s0 on the fly), LDS transpose -> coalesced
//   write + dots D[K][j]. t = colsum(s0*xr).
template <int K>
__global__ __launch_bounds__(512, 4) void step_kernel(
        const float* __restrict__ v, const float* __restrict__ s0,
        const unsigned short* __restrict__ Whs, const unsigned short* __restrict__ Wls,
        unsigned short* __restrict__ Qb, float* __restrict__ acc,
        float* __restrict__ w) {
    // union: main loop uses 8 staging buffers (40 KB); epilogue tred/wt (68 KB)
    __shared__ __align__(16) char smem_u[69632];
    short* Pbuf[2][2];  // [hi/lo][dbuf]
    short* Sbuf[2][2];
    Pbuf[0][0] = (short*)smem_u;                 Pbuf[0][1] = (short*)(smem_u + 5120);
    Pbuf[1][0] = (short*)(smem_u + 10240);       Pbuf[1][1] = (short*)(smem_u + 15360);
    Sbuf[0][0] = (short*)(smem_u + 20480);       Sbuf[0][1] = (short*)(smem_u + 25600);
    Sbuf[1][0] = (short*)(smem_u + 30720);       Sbuf[1][1] = (short*)(smem_u + 35840);
    float* tredf = (float*)smem_u;               // [32][WTS] (after main loop)
    float* wt    = (float*)smem_u;               // [256][WTS] (after ts extracted)
    __shared__ float ts[NT];
    __shared__ float nred[8];
    __shared__ float dred[8][8];

    const int tid = threadIdx.x;
    const int lane = tid & 63, wvi = tid >> 6;
    const int b = blockIdx.y;
    const int sbase = blockIdx.x * NT;
    const size_t boff = (size_t)b * FB;
    const int mbase = wvi * 32;
    const int cch = tid >> 4;          // 0..31: channel within chunk
    const int pos4 = (tid & 15) * 4;   // 0..60
    const int codd = cch & 1;
    const int c2s = cch >> 1;          // 0..15: 4-byte slot index

    // ---- CGS coefficients from previous step's dots ----
    float cj[K > 0 ? K : 1];
    if (K > 0) {
        float mm[K > 0 ? K : 1];
        mm[0] = sqrtf(acc[512 + b]);
#pragma unroll
        for (int j = 1; j < K; ++j) mm[j] = sqrtf(acc[512 + j * 8 + b]) + EPSK * mm[j - 1];
#pragma unroll
        for (int j = 0; j < K; ++j)
            cj[j] = acc[((K - 1) * 8 + j) * 8 + b] / (mm[j] * mm[j]);
    }
    unsigned short* QK = Qb + (size_t)(K > 0 ? K - 1 : 0) * NTOT;

    float tp[4] = {0.f, 0.f, 0.f, 0.f};
    float np = 0.f;

    // paired-write helper: x01 = val(pos4)|val(pos4+1)<<16 of THIS channel, etc.
    // writes word {even-ch | odd-ch<<16} at 2 positions; XOR-swizzled slot.
    auto wr2 = [&](short* buf, unsigned x01, unsigned x23) {
        unsigned p01 = (unsigned)__shfl_xor((int)x01, 16);
        unsigned p23 = (unsigned)__shfl_xor((int)x23, 16);
        unsigned mine = codd ? x23 : x01;
        unsigned theirs = codd ? p23 : p01;
        unsigned w0, w1;
        if (codd) {
            w0 = (theirs & 0xFFFFu) | (mine << 16);
            w1 = (theirs >> 16) | (mine & 0xFFFF0000u);
        } else {
            w0 = (mine & 0xFFFFu) | (theirs << 16);
            w1 = (mine >> 16) | (theirs & 0xFFFF0000u);
        }
        int P0 = pos4 + 2 * codd;                 // P0, P0+1 share (P>>3)
        int slot = c2s ^ (((P0 >> 3) & 3) << 2);
        *(unsigned*)(buf + P0 * RS + slot * 2) = w0;
        *(unsigned*)(buf + (P0 + 1) * RS + slot * 2) = w1;
    };

    // in-register prefetch set for one chunk (issued early, consumed late)
    struct Ld {
        float4 s4, w4, v4;
        ushort4 q[K > 1 ? K - 1 : 1];
    };
    auto issue = [&](int kc) -> Ld {
        Ld L;
        const size_t oe = boff + (size_t)(kc * 32 + cch) * HWn + sbase + pos4;
        L.s4 = *(const float4*)(s0 + oe);
        if (K == 0) {
            L.v4 = *(const float4*)(v + oe);
        } else {
            L.w4 = *(const float4*)(w + oe);
            L.v4 = *(const float4*)(v + oe);
#pragma unroll
            for (int j = 1; j < K; ++j)
                L.q[j - 1] = *(const ushort4*)(Qb + (size_t)(j - 1) * NTOT + oe);
        }
        return L;
    };
    auto consume = [&](Ld& L, int kc, int bb) {
        const size_t oe = boff + (size_t)(kc * 32 + cch) * HWn + sbase + pos4;
        float se[4] = {L.s4.x, L.s4.y, L.s4.z, L.s4.w};
        float xr[4];
        if (K == 0) {
            xr[0] = L.v4.x; xr[1] = L.v4.y; xr[2] = L.v4.z; xr[3] = L.v4.w;
        } else {
            float xe[4];
            xe[0] = fmaf(-cj[0], L.v4.x, L.w4.x);
            xe[1] = fmaf(-cj[0], L.v4.y, L.w4.y);
            xe[2] = fmaf(-cj[0], L.v4.z, L.w4.z);
            xe[3] = fmaf(-cj[0], L.v4.w, L.w4.w);
#pragma unroll
            for (int j = 1; j < K; ++j) {
                xe[0] = fmaf(-cj[j], b2f(L.q[j - 1].x), xe[0]);
                xe[1] = fmaf(-cj[j], b2f(L.q[j - 1].y), xe[1]);
                xe[2] = fmaf(-cj[j], b2f(L.q[j - 1].z), xe[2]);
                xe[3] = fmaf(-cj[j], b2f(L.q[j - 1].w), xe[3]);
            }
            unsigned h0 = f2b(xe[0]), h1 = f2b(xe[1]);
            unsigned h2 = f2b(xe[2]), h3 = f2b(xe[3]);
            ushort4 o;
            o.x = (unsigned short)h0; o.y = (unsigned short)h1;
            o.z = (unsigned short)h2; o.w = (unsigned short)h3;
            *(ushort4*)(QK + oe) = o;
            xr[0] = b2f(h0); xr[1] = b2f(h1); xr[2] = b2f(h2); xr[3] = b2f(h3);
        }
        unsigned phx[4], plx[4], shx[4], slx[4];
#pragma unroll
        for (int i = 0; i < 4; ++i) {
            np = fmaf(xr[i], xr[i], np);
            tp[i] = fmaf(xr[i], se[i], tp[i]);
            float pe = se[i] * xr[i];
            unsigned hp = f2b(pe);
            phx[i] = hp; plx[i] = f2b(pe - b2f((unsigned short)hp));
            unsigned hs = f2b(se[i]);
            shx[i] = hs; slx[i] = f2b(se[i] - b2f((unsigned short)hs));
        }
        wr2(Pbuf[0][bb], phx[0] | (phx[1] << 16), phx[2] | (phx[3] << 16));
        wr2(Pbuf[1][bb], plx[0] | (plx[1] << 16), plx[2] | (plx[3] << 16));
        wr2(Sbuf[0][bb], shx[0] | (shx[1] << 16), shx[2] | (shx[3] << 16));
        wr2(Sbuf[1][bb], slx[0] | (slx[1] << 16), slx[2] | (slx[3] << 16));
    };

    f32x4 ac[2][4], az[2][4];
#pragma unroll
    for (int i = 0; i < 2; ++i)
#pragma unroll
        for (int j = 0; j < 4; ++j) {
            ac[i][j] = (f32x4){0.f, 0.f, 0.f, 0.f};
            az[i][j] = (f32x4){0.f, 0.f, 0.f, 0.f};
        }

    const int r15 = lane & 15, qq = lane >> 4;
    {   // prologue: chunk 0 staged synchronously
        Ld L0 = issue(0);
        consume(L0, 0, 0);
    }
    for (int kc = 0; kc < 8; ++kc) {
        __syncthreads();               // buf[kc&1] staged; buf[kc^1] reads done
        // W fragments for THIS chunk — issued before the prefetch so their
        // (in-order) vmcnt wait does not force the prefetch loads to land.
        bf16x8 ah[2], al[2];
#pragma unroll
        for (int rt = 0; rt < 2; ++rt) {
            int mt = (mbase >> 4) + rt;
            ah[rt] = *(const bf16x8*)(Whs + (size_t)kc * 8192 + (mt * 64 + lane) * 8);
            al[rt] = *(const bf16x8*)(Wls + (size_t)kc * 8192 + (mt * 64 + lane) * 8);
        }
        Ld Ln;
        if (kc < 7) Ln = issue(kc + 1);   // fire next-chunk loads, no wait
        const short* ph = Pbuf[0][kc & 1];
        const short* pl = Pbuf[1][kc & 1];
        const short* sh = Sbuf[0][kc & 1];
        const short* sl = Sbuf[1][kc & 1];
#pragma unroll
        for (int ct = 0; ct < 4; ++ct) {
            int n = ct * 16 + r15;
            int grp = qq ^ ((n >> 3) & 3);
            int off = n * RS + grp * 8;
            bf16x8 bh = *(const bf16x8*)(ph + off);
            bf16x8 bl = *(const bf16x8*)(pl + off);
            bf16x8 svh = *(const bf16x8*)(sh + off);
            bf16x8 svl = *(const bf16x8*)(sl + off);
#pragma unroll
            for (int rt = 0; rt < 2; ++rt) {
                ac[rt][ct] = __builtin_amdgcn_mfma_f32_16x16x32_bf16(ah[rt], bh, ac[rt][ct], 0, 0, 0);
                ac[rt][ct] = __builtin_amdgcn_mfma_f32_16x16x32_bf16(ah[rt], bl, ac[rt][ct], 0, 0, 0);
                ac[rt][ct] = __builtin_amdgcn_mfma_f32_16x16x32_bf16(al[rt], bh, ac[rt][ct], 0, 0, 0);
                az[rt][ct] = __builtin_amdgcn_mfma_f32_16x16x32_bf16(ah[rt], svh, az[rt][ct], 0, 0, 0);
                az[rt][ct] = __builtin_amdgcn_mfma_f32_16x16x32_bf16(ah[rt], svl, az[rt][ct], 0, 0, 0);
                az[rt][ct] = __builtin_amdgcn_mfma_f32_16x16x32_bf16(al[rt], svh, az[rt][ct], 0, 0, 0);
            }
        }
        if (kc < 7) consume(Ln, kc + 1, (kc + 1) & 1);  // vmcnt wait lands HERE
    }

    // ---- t / norm reductions (tred aliases staging area; MFMA reads done) ----
    __syncthreads();
    *(float4*)(tredf + cch * WTS + pos4) = *(float4*)tp;
    {
        float q2 = np;
        for (int off2 = 32; off2 > 0; off2 >>= 1) q2 += __shfl_down(q2, off2);
        if (lane == 0) nred[wvi] = q2;
    }
    __syncthreads();
    if (tid < NT) {
        float s = 0.f;
#pragma unroll
        for (int g = 0; g < 32; ++g) s += tredf[g * WTS + tid];
        ts[tid] = s;
    }
    if (tid == 0)
        atomicAdd(&acc[512 + K * 8 + b],
                  nred[0] + nred[1] + nred[2] + nred[3] +
                  nred[4] + nred[5] + nred[6] + nred[7]);
    __syncthreads();

    // ---- w' = ac - az*t into LDS transpose tile ----
#pragma unroll
    for (int rt = 0; rt < 2; ++rt)
#pragma unroll
        for (int ct = 0; ct < 4; ++ct) {
            int col = ct * 16 + r15;
            int r0 = mbase + rt * 16 + qq * 4;
            float tv = ts[col];
#pragma unroll
            for (int reg = 0; reg < 4; ++reg)
                wt[(r0 + reg) * WTS + col] = ac[rt][ct][reg] - az[rt][ct][reg] * tv;
        }
    __syncthreads();

    // ---- coalesced global write + dots D[K][j] ----
    float dp[K + 1];
#pragma unroll
    for (int j = 0; j <= K; ++j) dp[j] = 0.f;
#pragma unroll
    for (int rr = 0; rr < 8; ++rr) {
        int row = rr * 32 + (tid >> 4);
        int col = (tid & 15) * 4;
        float4 wv4 = *(const float4*)(wt + row * WTS + col);
        size_t idx = boff + (size_t)row * HWn + sbase + col;
        *(float4*)(w + idx) = wv4;
        float4 vv4 = *(const float4*)(v + idx);
        dp[0] = fmaf(wv4.x, vv4.x, dp[0]);
        dp[0] = fmaf(wv4.y, vv4.y, dp[0]);
        dp[0] = fmaf(wv4.z, vv4.z, dp[0]);
        dp[0] = fmaf(wv4.w, vv4.w, dp[0]);
#pragma unroll
        for (int j = 1; j <= K; ++j) {
            ushort4 u = *(const ushort4*)(Qb + (size_t)(j - 1) * NTOT + idx);
            dp[j] = fmaf(wv4.x, b2f(u.x), dp[j]);
            dp[j] = fmaf(wv4.y, b2f(u.y), dp[j]);
            dp[j] = fmaf(wv4.z, b2f(u.z), dp[j]);
            dp[j] = fmaf(wv4.w, b2f(u.w), dp[j]);
        }
    }
#pragma unroll
    for (int j = 0; j <= K; ++j) {
        float q2 = dp[j];
        for (int off2 = 32; off2 > 0; off2 >>= 1) q2 += __shfl_down(q2, off2);
        if (lane == 0) dred[wvi][j] = q2;
    }
    __syncthreads();
    if (tid <= K)
        atomicAdd(&acc[(K * 8 + tid) * 8 + b],
                  dred[0][tid] + dred[1][tid] + dred[2][tid] + dred[3][tid] +
                  dred[4][tid] + dred[5][tid] + dred[6][tid] + dred[7][tid]);
}

// ---------------- expm of 9x9 per batch (fp64); emits combine coeffs ----------
__global__ __launch_bounds__(128) void expm_kernel(const float* __restrict__ acc,
                                                   float* __restrict__ coordsOut) {
    __shared__ double Am[81], Pm[81], Tm[81];
    __shared__ double ssc;
    __shared__ int sn;
    const int b = blockIdx.x;
    const int t = threadIdx.x;
    const int r = t / 9, c = t % 9;
    double m[8];
    m[0] = sqrt((double)acc[512 + b]);
    for (int j = 1; j < 8; ++j) m[j] = sqrt((double)acc[512 + j * 8 + b]) + 1e-12 * m[j - 1];
    if (t < 81) {
        double val = 0.0;
        if (r < 8 && c < 8) {
            if (r <= c) val = TEND * (double)acc[(c * 8 + r) * 8 + b] / (m[r] * m[c]);
            else if (r == c + 1) val = TEND * sqrt((double)acc[512 + r * 8 + b]) / m[c];
        }
        if (r == 0 && c == 8) val = TEND;
        Am[t] = val;
    }
    __syncthreads();
    if (t == 0) {
        double mx = 0.0;
        for (int rr = 0; rr < 9; ++rr) {
            double s = 0.0;
            for (int cc = 0; cc < 9; ++cc) s += fabs(Am[rr * 9 + cc]);
            if (s > mx) mx = s;
        }
        int n = 0;
        while (mx > 0.25 && n < 48) { mx *= 0.5; ++n; }
        double sc = 1.0;
        for (int ii = 0; ii < n; ++ii) sc *= 0.5;
        sn = n; ssc = sc;
    }
    __syncthreads();
    if (t < 81) Am[t] *= ssc;
    __syncthreads();
    if (t < 81) Pm[t] = (r == c) ? 1.0 : 0.0;
    __syncthreads();
    for (int i = 20; i >= 1; --i) {
        if (t < 81) {
            double s = 0.0;
            for (int k = 0; k < 9; ++k) s += Am[r * 9 + k] * Pm[k * 9 + c];
            Tm[t] = ((r == c) ? 1.0 : 0.0) + s / (double)i;
        }
        __syncthreads();
        if (t < 81) Pm[t] = Tm[t];
        __syncthreads();
    }
    int n = sn;
    for (int q = 0; q < n; ++q) {
        if (t < 81) {
            double s = 0.0;
            for (int k = 0; k < 9; ++k) s += Pm[r * 9 + k] * Pm[k * 9 + c];
            Tm[t] = s;
        }
        __syncthreads();
        if (t < 81) Pm[t] = Tm[t];
        __syncthreads();
    }
    if (t < 8) coordsOut[b * 8 + t] = (float)(Pm[t * 9 + 8] * m[0] / m[t]);
}

__device__ inline void unp8(uint4 u, float* f) {
    f[0] = b2f(u.x & 0xFFFFu); f[1] = b2f(u.x >> 16);
    f[2] = b2f(u.y & 0xFFFFu); f[3] = b2f(u.y >> 16);
    f[4] = b2f(u.z & 0xFFFFu); f[5] = b2f(u.z >> 16);
    f[6] = b2f(u.w & 0xFFFFu); f[7] = b2f(u.w >> 16);
}

// ------ out = coeff_0*v + sum_{j=1..7} coeff_j * U_j (bf16) ------
__global__ __launch_bounds__(256) void combine_kernel(const unsigned short* __restrict__ Qb,
                                                      const float* __restrict__ v,
                                                      const float* __restrict__ coords,
                                                      float* __restrict__ out) {
    int b = blockIdx.y;
    const size_t boff = (size_t)b * FB;
    float cf[8];
#pragma unroll
    for (int j = 0; j < 8; ++j) cf[j] = coords[b * 8 + j];
    const float4* vv = (const float4*)(v + boff);
    const uint4* uv[8];
#pragma unroll
    for (int j = 1; j < 8; ++j)
        uv[j] = (const uint4*)(Qb + (size_t)(j - 1) * NTOT + boff);
    int i = blockIdx.x * 256 + threadIdx.x;
    float4* ov = (float4*)(out + boff);
#pragma unroll
    for (int r = 0; r < 2; ++r) {
        int idx = i + r * 65536;
        float4 v0 = vv[2 * idx], v1 = vv[2 * idx + 1];
        float a[8] = {cf[0] * v0.x, cf[0] * v0.y, cf[0] * v0.z, cf[0] * v0.w,
                      cf[0] * v1.x, cf[0] * v1.y, cf[0] * v1.z, cf[0] * v1.w};
#pragma unroll
        for (int j = 1; j < 8; ++j) {
            uint4 u = uv[j][idx];
            float ue[8]; unp8(u, ue);
#pragma unroll
            for (int e = 0; e < 8; ++e) a[e] = fmaf(cf[j], ue[e], a[e]);
        }
        float4 o0 = {a[0], a[1], a[2], a[3]};
        float4 o1 = {a[4], a[5], a[6], a[7]};
        ov[2 * idx] = o0; ov[2 * idx + 1] = o1;
    }
}

extern "C" void kernel_launch(void* const* d_in, const int* in_sizes, int n_in,
                              void* d_out, int out_size, void* d_ws, size_t ws_size,
                              hipStream_t stream) {
    const float* s0 = (const float*)d_in[0];
    const float* v  = (const float*)d_in[1];
    const float* W  = (const float*)d_in[2];
    float* out = (float*)d_out;

    // ws (floats): [acc 576 | coords 64 | pad->1024 | Whs 32768 | Wls 32768 |
    //               Qb bf16 7*NTOT]
    float* ws     = (float*)d_ws;
    float* acc    = ws;
    float* coords = ws + 576;
    unsigned short* Whs = (unsigned short*)(ws + 1024);
    unsigned short* Wls = Whs + 65536;
    unsigned short* Qb  = (unsigned short*)(ws + 1024 + 65536);  // 7 bf16 fields
    float* w      = out;   // working A-output (fp32), updated in place per step

    init_kernel<<<dim3(1), dim3(256), 0, stream>>>(ws);
    wsplit_kernel<<<dim3(8, 16), dim3(64), 0, stream>>>(W, Whs, Wls);

    dim3 ga(64, 8), blk(512);
#define STEPK(K) step_kernel<K><<<ga, blk, 0, stream>>>(v, s0, Whs, Wls, Qb, acc, w);
    STEPK(0) STEPK(1) STEPK(2) STEPK(3) STEPK(4) STEPK(5) STEPK(6) STEPK(7)
#undef STEPK

    expm_kernel<<<dim3(8), dim3(128), 0, stream>>>(acc, coords);
    combine_kernel<<<dim3(256, 8), dim3(256), 0, stream>>>(Qb, v, coords, out);
}

// Round 9
// 547.133 us; speedup vs baseline: 1.9051x; 1.9051x over previous
//
#include <hip/hip_runtime.h>
#include <math.h>

#define Bn   8
#define Cn   256
#define HWn  4096
#define FB   (Cn * HWn)      // 1048576 elems per batch-field
#define NTOT (Bn * FB)       // 8388608 elems per field
#define TEND 1.0
#define EPSK 1e-12f
#define NT   64              // apply N-tile (positions) — full 256B lines
#define RS   40              // staging row stride (shorts); 16 data slots + pad
#define WTS  68              // wt / tred row stride (floats)

typedef float f32x4 __attribute__((ext_vector_type(4)));
typedef short bf16x8 __attribute__((ext_vector_type(8)));

__device__ inline float b2f(unsigned int u) {
    return __uint_as_float(u << 16);
}
__device__ inline unsigned short f2b(float f) {  // RNE
    unsigned u = __float_as_uint(f);
    unsigned r = u + 0x7FFFu + ((u >> 16) & 1u);
    return (unsigned short)(r >> 16);
}

// acc layout (floats, 8 batches each):
//   D[k][j] at acc[(k*8+j)*8 + b];  Nsq[j] at acc[512 + j*8 + b];  coords at acc+576

__global__ void init_kernel(float* __restrict__ p) {
    for (int i = threadIdx.x; i < 1024; i += 256) p[i] = 0.0f;
}

// ---- split W into bf16 hi/lo in MFMA-A staged layout ----
// layout: Whs[((kc*16+mt)*64+lane)*8+j] = bf16 of W[mt*16+(lane&15)][kc*32+(lane>>4)*8+j]
__global__ void wsplit_kernel(const float* __restrict__ W,
                              unsigned short* __restrict__ Whs,
                              unsigned short* __restrict__ Wls) {
    int kc = blockIdx.x, mt = blockIdx.y, l = threadIdx.x;
    int m = mt * 16 + (l & 15);
    int k0 = kc * 32 + (l >> 4) * 8;
#pragma unroll
    for (int j = 0; j < 8; ++j) {
        float wv = W[m * 256 + k0 + j];
        unsigned short h = f2b(wv);
        unsigned short lo = f2b(wv - b2f(h));
        int idx = ((kc * 16 + mt) * 64 + l) * 8 + j;
        Whs[idx] = h; Wls[idx] = lo;
    }
}

// ================= fused Krylov step K (K = 0..7), 512-thread blocks ===========
// One block per (tile, batch): 8 waves x 32 rows, 2 blocks/CU.
// TOOLCHAIN RULE (r6/r8 post-mortems): 512-thread blocks MUST use
// __launch_bounds__(512,2). (512,4) caps VGPR at 64 on this compiler ->
// accumulators spill to scratch (VGPR_Count=64, WRITE 242/336 MB, 127-230us).
// (512,2) -> cap 128; r7 compiled to 88 VGPR, no spill.
// ASYNC-STAGE SPLIT: per k-chunk, global loads for chunk kc+1 are ISSUED into
// registers before the MFMAs of chunk kc, and CONSUMED (vmcnt wait + CGS + LDS
// write) after them — HBM latency hides under MFMA. W-fragment loads issued
// before the prefetch so their in-order vmcnt wait doesn't drain the prefetch.
//   x = w - sum cj*basis (CGS) -> Q_{K-1} bf16; P = s0*xr, S = s0 staged hi/lo
//   (XOR-swizzled LDS, shfl-paired b32 writes); MFMA: ac += W@P, az += W@S.
// Epilogue: w' = ac - az*t (Z = W@s0 on the fly), LDS transpose -> coalesced
//   write + dots D[K][j]. t = colsum(s0*xr).
template <int K>
__global__ __launch_bounds__(512, 2) void step_kernel(
        const float* __restrict__ v, const float* __restrict__ s0,
        const unsigned short* __restrict__ Whs, const unsigned short* __restrict__ Wls,
        unsigned short* __restrict__ Qb, float* __restrict__ acc,
        float* __restrict__ w) {
    // union: main loop uses 8 staging buffers (40 KB); epilogue tred/wt (68 KB)
    __shared__ __align__(16) char smem_u[69632];
    short* Pbuf[2][2];  // [hi/lo][dbuf]
    short* Sbuf[2][2];
    Pbuf[0][0] = (short*)smem_u;                 Pbuf[0][1] = (short*)(smem_u + 5120);
    Pbuf[1][0] = (short*)(smem_u + 10240);       Pbuf[1][1] = (short*)(smem_u + 15360);
    Sbuf[0][0] = (short*)(smem_u + 20480);       Sbuf[0][1] = (short*)(smem_u + 25600);
    Sbuf[1][0] = (short*)(smem_u + 30720);       Sbuf[1][1] = (short*)(smem_u + 35840);
    float* tredf = (float*)smem_u;               // [32][WTS] (after main loop)
    float* wt    = (float*)smem_u;               // [256][WTS] (after ts extracted)
    __shared__ float ts[NT];
    __shared__ float nred[8];
    __shared__ float dred[8][8];

    const int tid = threadIdx.x;
    const int lane = tid & 63, wvi = tid >> 6;
    const int b = blockIdx.y;
    const int sbase = blockIdx.x * NT;
    const size_t boff = (size_t)b * FB;
    const int mbase = wvi * 32;
    const int cch = tid >> 4;          // 0..31: channel within chunk
    const int pos4 = (tid & 15) * 4;   // 0..60
    const int codd = cch & 1;
    const int c2s = cch >> 1;          // 0..15: 4-byte slot index

    // ---- CGS coefficients from previous step's dots ----
    float cj[K > 0 ? K : 1];
    if (K > 0) {
        float mm[K > 0 ? K : 1];
        mm[0] = sqrtf(acc[512 + b]);
#pragma unroll
        for (int j = 1; j < K; ++j) mm[j] = sqrtf(acc[512 + j * 8 + b]) + EPSK * mm[j - 1];
#pragma unroll
        for (int j = 0; j < K; ++j)
            cj[j] = acc[((K - 1) * 8 + j) * 8 + b] / (mm[j] * mm[j]);
    }
    unsigned short* QK = Qb + (size_t)(K > 0 ? K - 1 : 0) * NTOT;

    float tp[4] = {0.f, 0.f, 0.f, 0.f};
    float np = 0.f;

    // paired-write helper: x01 = val(pos4)|val(pos4+1)<<16 of THIS channel, etc.
    // writes word {even-ch | odd-ch<<16} at 2 positions; XOR-swizzled slot.
    auto wr2 = [&](short* buf, unsigned x01, unsigned x23) {
        unsigned p01 = (unsigned)__shfl_xor((int)x01, 16);
        unsigned p23 = (unsigned)__shfl_xor((int)x23, 16);
        unsigned mine = codd ? x23 : x01;
        unsigned theirs = codd ? p23 : p01;
        unsigned w0, w1;
        if (codd) {
            w0 = (theirs & 0xFFFFu) | (mine << 16);
            w1 = (theirs >> 16) | (mine & 0xFFFF0000u);
        } else {
            w0 = (mine & 0xFFFFu) | (theirs << 16);
            w1 = (mine >> 16) | (theirs & 0xFFFF0000u);
        }
        int P0 = pos4 + 2 * codd;                 // P0, P0+1 share (P>>3)
        int slot = c2s ^ (((P0 >> 3) & 3) << 2);
        *(unsigned*)(buf + P0 * RS + slot * 2) = w0;
        *(unsigned*)(buf + (P0 + 1) * RS + slot * 2) = w1;
    };

    // in-register prefetch set for one chunk (issued early, consumed late)
    struct Ld {
        float4 s4, w4, v4;
        ushort4 q[K > 1 ? K - 1 : 1];
    };
    auto issue = [&](int kc) -> Ld {
        Ld L;
        const size_t oe = boff + (size_t)(kc * 32 + cch) * HWn + sbase + pos4;
        L.s4 = *(const float4*)(s0 + oe);
        if (K == 0) {
            L.v4 = *(const float4*)(v + oe);
        } else {
            L.w4 = *(const float4*)(w + oe);
            L.v4 = *(const float4*)(v + oe);
#pragma unroll
            for (int j = 1; j < K; ++j)
                L.q[j - 1] = *(const ushort4*)(Qb + (size_t)(j - 1) * NTOT + oe);
        }
        return L;
    };
    auto consume = [&](Ld& L, int kc, int bb) {
        const size_t oe = boff + (size_t)(kc * 32 + cch) * HWn + sbase + pos4;
        float se[4] = {L.s4.x, L.s4.y, L.s4.z, L.s4.w};
        float xr[4];
        if (K == 0) {
            xr[0] = L.v4.x; xr[1] = L.v4.y; xr[2] = L.v4.z; xr[3] = L.v4.w;
        } else {
            float xe[4];
            xe[0] = fmaf(-cj[0], L.v4.x, L.w4.x);
            xe[1] = fmaf(-cj[0], L.v4.y, L.w4.y);
            xe[2] = fmaf(-cj[0], L.v4.z, L.w4.z);
            xe[3] = fmaf(-cj[0], L.v4.w, L.w4.w);
#pragma unroll
            for (int j = 1; j < K; ++j) {
                xe[0] = fmaf(-cj[j], b2f(L.q[j - 1].x), xe[0]);
                xe[1] = fmaf(-cj[j], b2f(L.q[j - 1].y), xe[1]);
                xe[2] = fmaf(-cj[j], b2f(L.q[j - 1].z), xe[2]);
                xe[3] = fmaf(-cj[j], b2f(L.q[j - 1].w), xe[3]);
            }
            unsigned h0 = f2b(xe[0]), h1 = f2b(xe[1]);
            unsigned h2 = f2b(xe[2]), h3 = f2b(xe[3]);
            ushort4 o;
            o.x = (unsigned short)h0; o.y = (unsigned short)h1;
            o.z = (unsigned short)h2; o.w = (unsigned short)h3;
            *(ushort4*)(QK + oe) = o;
            xr[0] = b2f(h0); xr[1] = b2f(h1); xr[2] = b2f(h2); xr[3] = b2f(h3);
        }
        unsigned phx[4], plx[4], shx[4], slx[4];
#pragma unroll
        for (int i = 0; i < 4; ++i) {
            np = fmaf(xr[i], xr[i], np);
            tp[i] = fmaf(xr[i], se[i], tp[i]);
            float pe = se[i] * xr[i];
            unsigned hp = f2b(pe);
            phx[i] = hp; plx[i] = f2b(pe - b2f((unsigned short)hp));
            unsigned hs = f2b(se[i]);
            shx[i] = hs; slx[i] = f2b(se[i] - b2f((unsigned short)hs));
        }
        wr2(Pbuf[0][bb], phx[0] | (phx[1] << 16), phx[2] | (phx[3] << 16));
        wr2(Pbuf[1][bb], plx[0] | (plx[1] << 16), plx[2] | (plx[3] << 16));
        wr2(Sbuf[0][bb], shx[0] | (shx[1] << 16), shx[2] | (shx[3] << 16));
        wr2(Sbuf[1][bb], slx[0] | (slx[1] << 16), slx[2] | (slx[3] << 16));
    };

    f32x4 ac[2][4], az[2][4];
#pragma unroll
    for (int i = 0; i < 2; ++i)
#pragma unroll
        for (int j = 0; j < 4; ++j) {
            ac[i][j] = (f32x4){0.f, 0.f, 0.f, 0.f};
            az[i][j] = (f32x4){0.f, 0.f, 0.f, 0.f};
        }

    const int r15 = lane & 15, qq = lane >> 4;
    {   // prologue: chunk 0 staged synchronously
        Ld L0 = issue(0);
        consume(L0, 0, 0);
    }
    for (int kc = 0; kc < 8; ++kc) {
        __syncthreads();               // buf[kc&1] staged; buf[kc^1] reads done
        // W fragments for THIS chunk — issued before the prefetch so their
        // (in-order) vmcnt wait does not force the prefetch loads to land.
        bf16x8 ah[2], al[2];
#pragma unroll
        for (int rt = 0; rt < 2; ++rt) {
            int mt = (mbase >> 4) + rt;
            ah[rt] = *(const bf16x8*)(Whs + (size_t)kc * 8192 + (mt * 64 + lane) * 8);
            al[rt] = *(const bf16x8*)(Wls + (size_t)kc * 8192 + (mt * 64 + lane) * 8);
        }
        Ld Ln;
        if (kc < 7) Ln = issue(kc + 1);   // fire next-chunk loads, no wait
        const short* ph = Pbuf[0][kc & 1];
        const short* pl = Pbuf[1][kc & 1];
        const short* sh = Sbuf[0][kc & 1];
        const short* sl = Sbuf[1][kc & 1];
#pragma unroll
        for (int ct = 0; ct < 4; ++ct) {
            int n = ct * 16 + r15;
            int grp = qq ^ ((n >> 3) & 3);
            int off = n * RS + grp * 8;
            bf16x8 bh = *(const bf16x8*)(ph + off);
            bf16x8 bl = *(const bf16x8*)(pl + off);
            bf16x8 svh = *(const bf16x8*)(sh + off);
            bf16x8 svl = *(const bf16x8*)(sl + off);
#pragma unroll
            for (int rt = 0; rt < 2; ++rt) {
                ac[rt][ct] = __builtin_amdgcn_mfma_f32_16x16x32_bf16(ah[rt], bh, ac[rt][ct], 0, 0, 0);
                ac[rt][ct] = __builtin_amdgcn_mfma_f32_16x16x32_bf16(ah[rt], bl, ac[rt][ct], 0, 0, 0);
                ac[rt][ct] = __builtin_amdgcn_mfma_f32_16x16x32_bf16(al[rt], bh, ac[rt][ct], 0, 0, 0);
                az[rt][ct] = __builtin_amdgcn_mfma_f32_16x16x32_bf16(ah[rt], svh, az[rt][ct], 0, 0, 0);
                az[rt][ct] = __builtin_amdgcn_mfma_f32_16x16x32_bf16(ah[rt], svl, az[rt][ct], 0, 0, 0);
                az[rt][ct] = __builtin_amdgcn_mfma_f32_16x16x32_bf16(al[rt], svh, az[rt][ct], 0, 0, 0);
            }
        }
        if (kc < 7) consume(Ln, kc + 1, (kc + 1) & 1);  // vmcnt wait lands HERE
    }

    // ---- t / norm reductions (tred aliases staging area; MFMA reads done) ----
    __syncthreads();
    *(float4*)(tredf + cch * WTS + pos4) = *(float4*)tp;
    {
        float q2 = np;
        for (int off2 = 32; off2 > 0; off2 >>= 1) q2 += __shfl_down(q2, off2);
        if (lane == 0) nred[wvi] = q2;
    }
    __syncthreads();
    if (tid < NT) {
        float s = 0.f;
#pragma unroll
        for (int g = 0; g < 32; ++g) s += tredf[g * WTS + tid];
        ts[tid] = s;
    }
    if (tid == 0)
        atomicAdd(&acc[512 + K * 8 + b],
                  nred[0] + nred[1] + nred[2] + nred[3] +
                  nred[4] + nred[5] + nred[6] + nred[7]);
    __syncthreads();

    // ---- w' = ac - az*t into LDS transpose tile ----
#pragma unroll
    for (int rt = 0; rt < 2; ++rt)
#pragma unroll
        for (int ct = 0; ct < 4; ++ct) {
            int col = ct * 16 + r15;
            int r0 = mbase + rt * 16 + qq * 4;
            float tv = ts[col];
#pragma unroll
            for (int reg = 0; reg < 4; ++reg)
                wt[(r0 + reg) * WTS + col] = ac[rt][ct][reg] - az[rt][ct][reg] * tv;
        }
    __syncthreads();

    // ---- coalesced global write + dots D[K][j] ----
    float dp[K + 1];
#pragma unroll
    for (int j = 0; j <= K; ++j) dp[j] = 0.f;
#pragma unroll
    for (int rr = 0; rr < 8; ++rr) {
        int row = rr * 32 + (tid >> 4);
        int col = (tid & 15) * 4;
        float4 wv4 = *(const float4*)(wt + row * WTS + col);
        size_t idx = boff + (size_t)row * HWn + sbase + col;
        *(float4*)(w + idx) = wv4;
        float4 vv4 = *(const float4*)(v + idx);
        dp[0] = fmaf(wv4.x, vv4.x, dp[0]);
        dp[0] = fmaf(wv4.y, vv4.y, dp[0]);
        dp[0] = fmaf(wv4.z, vv4.z, dp[0]);
        dp[0] = fmaf(wv4.w, vv4.w, dp[0]);
#pragma unroll
        for (int j = 1; j <= K; ++j) {
            ushort4 u = *(const ushort4*)(Qb + (size_t)(j - 1) * NTOT + idx);
            dp[j] = fmaf(wv4.x, b2f(u.x), dp[j]);
            dp[j] = fmaf(wv4.y, b2f(u.y), dp[j]);
            dp[j] = fmaf(wv4.z, b2f(u.z), dp[j]);
            dp[j] = fmaf(wv4.w, b2f(u.w), dp[j]);
        }
    }
#pragma unroll
    for (int j = 0; j <= K; ++j) {
        float q2 = dp[j];
        for (int off2 = 32; off2 > 0; off2 >>= 1) q2 += __shfl_down(q2, off2);
        if (lane == 0) dred[wvi][j] = q2;
    }
    __syncthreads();
    if (tid <= K)
        atomicAdd(&acc[(K * 8 + tid) * 8 + b],
                  dred[0][tid] + dred[1][tid] + dred[2][tid] + dred[3][tid] +
                  dred[4][tid] + dred[5][tid] + dred[6][tid] + dred[7][tid]);
}

// ---------------- expm of 9x9 per batch (fp64); emits combine coeffs ----------
__global__ __launch_bounds__(128) void expm_kernel(const float* __restrict__ acc,
                                                   float* __restrict__ coordsOut) {
    __shared__ double Am[81], Pm[81], Tm[81];
    __shared__ double ssc;
    __shared__ int sn;
    const int b = blockIdx.x;
    const int t = threadIdx.x;
    const int r = t / 9, c = t % 9;
    double m[8];
    m[0] = sqrt((double)acc[512 + b]);
    for (int j = 1; j < 8; ++j) m[j] = sqrt((double)acc[512 + j * 8 + b]) + 1e-12 * m[j - 1];
    if (t < 81) {
        double val = 0.0;
        if (r < 8 && c < 8) {
            if (r <= c) val = TEND * (double)acc[(c * 8 + r) * 8 + b] / (m[r] * m[c]);
            else if (r == c + 1) val = TEND * sqrt((double)acc[512 + r * 8 + b]) / m[c];
        }
        if (r == 0 && c == 8) val = TEND;
        Am[t] = val;
    }
    __syncthreads();
    if (t == 0) {
        double mx = 0.0;
        for (int rr = 0; rr < 9; ++rr) {
            double s = 0.0;
            for (int cc = 0; cc < 9; ++cc) s += fabs(Am[rr * 9 + cc]);
            if (s > mx) mx = s;
        }
        int n = 0;
        while (mx > 0.25 && n < 48) { mx *= 0.5; ++n; }
        double sc = 1.0;
        for (int ii = 0; ii < n; ++ii) sc *= 0.5;
        sn = n; ssc = sc;
    }
    __syncthreads();
    if (t < 81) Am[t] *= ssc;
    __syncthreads();
    if (t < 81) Pm[t] = (r == c) ? 1.0 : 0.0;
    __syncthreads();
    for (int i = 20; i >= 1; --i) {
        if (t < 81) {
            double s = 0.0;
            for (int k = 0; k < 9; ++k) s += Am[r * 9 + k] * Pm[k * 9 + c];
            Tm[t] = ((r == c) ? 1.0 : 0.0) + s / (double)i;
        }
        __syncthreads();
        if (t < 81) Pm[t] = Tm[t];
        __syncthreads();
    }
    int n = sn;
    for (int q = 0; q < n; ++q) {
        if (t < 81) {
            double s = 0.0;
            for (int k = 0; k < 9; ++k) s += Pm[r * 9 + k] * Pm[k * 9 + c];
            Tm[t] = s;
        }
        __syncthreads();
        if (t < 81) Pm[t] = Tm[t];
        __syncthreads();
    }
    if (t < 8) coordsOut[b * 8 + t] = (float)(Pm[t * 9 + 8] * m[0] / m[t]);
}

__device__ inline void unp8(uint4 u, float* f) {
    f[0] = b2f(u.x & 0xFFFFu); f[1] = b2f(u.x >> 16);
    f[2] = b2f(u.y & 0xFFFFu); f[3] = b2f(u.y >> 16);
    f[4] = b2f(u.z & 0xFFFFu); f[5] = b2f(u.z >> 16);
    f[6] = b2f(u.w & 0xFFFFu); f[7] = b2f(u.w >> 16);
}

// ------ out = coeff_0*v + sum_{j=1..7} coeff_j * U_j (bf16) ------
__global__ __launch_bounds__(256) void combine_kernel(const unsigned short* __restrict__ Qb,
                                                      const float* __restrict__ v,
                                                      const float* __restrict__ coords,
                                                      float* __restrict__ out) {
    int b = blockIdx.y;
    const size_t boff = (size_t)b * FB;
    float cf[8];
#pragma unroll
    for (int j = 0; j < 8; ++j) cf[j] = coords[b * 8 + j];
    const float4* vv = (const float4*)(v + boff);
    const uint4* uv[8];
#pragma unroll
    for (int j = 1; j < 8; ++j)
        uv[j] = (const uint4*)(Qb + (size_t)(j - 1) * NTOT + boff);
    int i = blockIdx.x * 256 + threadIdx.x;
    float4* ov = (float4*)(out + boff);
#pragma unroll
    for (int r = 0; r < 2; ++r) {
        int idx = i + r * 65536;
        float4 v0 = vv[2 * idx], v1 = vv[2 * idx + 1];
        float a[8] = {cf[0] * v0.x, cf[0] * v0.y, cf[0] * v0.z, cf[0] * v0.w,
                      cf[0] * v1.x, cf[0] * v1.y, cf[0] * v1.z, cf[0] * v1.w};
#pragma unroll
        for (int j = 1; j < 8; ++j) {
            uint4 u = uv[j][idx];
            float ue[8]; unp8(u, ue);
#pragma unroll
            for (int e = 0; e < 8; ++e) a[e] = fmaf(cf[j], ue[e], a[e]);
        }
        float4 o0 = {a[0], a[1], a[2], a[3]};
        float4 o1 = {a[4], a[5], a[6], a[7]};
        ov[2 * idx] = o0; ov[2 * idx + 1] = o1;
    }
}

extern "C" void kernel_launch(void* const* d_in, const int* in_sizes, int n_in,
                              void* d_out, int out_size, void* d_ws, size_t ws_size,
                              hipStream_t stream) {
    const float* s0 = (const float*)d_in[0];
    const float* v  = (const float*)d_in[1];
    const float* W  = (const float*)d_in[2];
    float* out = (float*)d_out;

    // ws (floats): [acc 576 | coords 64 | pad->1024 | Whs 32768 | Wls 32768 |
    //               Qb bf16 7*NTOT]
    float* ws     = (float*)d_ws;
    float* acc    = ws;
    float* coords = ws + 576;
    unsigned short* Whs = (unsigned short*)(ws + 1024);
    unsigned short* Wls = Whs + 65536;
    unsigned short* Qb  = (unsigned short*)(ws + 1024 + 65536);  // 7 bf16 fields
    float* w      = out;   // working A-output (fp32), updated in place per step

    init_kernel<<<dim3(1), dim3(256), 0, stream>>>(ws);
    wsplit_kernel<<<dim3(8, 16), dim3(64), 0, stream>>>(W, Whs, Wls);

    dim3 ga(64, 8), blk(512);
#define STEPK(K) step_kernel<K><<<ga, blk, 0, stream>>>(v, s0, Whs, Wls, Qb, acc, w);
    STEPK(0) STEPK(1) STEPK(2) STEPK(3) STEPK(4) STEPK(5) STEPK(6) STEPK(7)
#undef STEPK

    expm_kernel<<<dim3(8), dim3(128), 0, stream>>>(acc, coords);
    combine_kernel<<<dim3(256, 8), dim3(256), 0, stream>>>(Qb, v, coords, out);
}